// Round 4
// baseline (182.751 us; speedup 1.0000x reference)
//
#include <hip/hip_runtime.h>

#define EPS 1e-5f

typedef float v2f __attribute__((ext_vector_type(2)));

constexpr int B = 32;
constexpr int H = 512;
constexpr int W = 512;
constexpr int NPIX = H * W;          // 262144
constexpr int P = 13;
constexpr int HP = H - P + 1;        // 500
constexpr int WP = W - P + 1;        // 500
constexpr int TILES_X = 8;           // 8 * 64 = 512 cols
constexpr int BAND_ROWS = 27;        // output rows per band
constexpr int BANDS_Y = 19;          // bands 0..17 emit rows 0..485; band 18 (y0=473) emits 486..499
constexpr int ITERS = BAND_ROWS + P - 1;   // 39 input rows per band
constexpr int STEADY = ITERS - 13;         // 26

// ws layout (floats): gs[5][B] global moment sums, then ps[B] patch cc sums

// ---------------------------------------------------------------------------
// Fused kernel, one wave per block.
//  - ONE __syncthreads() per row-step between LDS staging-write and the
//    13-tap reads. REQUIRED: cross-lane LDS reads without a barrier are
//    compiler-level UB (R2 NaN: clang reordered reads past the writes ->
//    uninitialized LDS -> negative "variance" -> rsqrt(neg)). The double
//    buffer makes the second barrier unnecessary.
//  - vertical 13-deep ring in REGISTERS (fully unrolled, compile-time slot)
//  - moment chains packed as float2 -> v_pk_{add,fma}_f32
//  - 2-row-deep global prefetch pipeline feeding the LDS row stage
//  - global-moment accumulation fused over owned (non-overlapping) region
// grid = 32*8*19 = 4864 single-wave blocks
// ---------------------------------------------------------------------------
__global__ __launch_bounds__(64) void ncc_fused_kernel(
    const float* __restrict__ x1, const float* __restrict__ x2,
    float* __restrict__ gs, float* __restrict__ ps) {
  int bid = blockIdx.x;
  int b = bid / (TILES_X * BANDS_Y);
  int rem = bid % (TILES_X * BANDS_Y);
  int tile = rem % TILES_X;
  int band = rem / TILES_X;
  bool last = (band == BANDS_Y - 1);
  int x0 = tile * 64;
  int y0 = last ? (HP - BAND_ROWS) : band * BAND_ROWS;  // 473 for last band
  int tid = threadIdx.x;
  bool valid = (x0 + tid) < WP;
  bool halo = tid < 12;

  __shared__ v2f st[2][80];  // double-buffered row stage, 76 used, 1.28 KB

  const float* b1 = x1 + (size_t)b * NPIX + (size_t)y0 * W;
  const float* b2 = x2 + (size_t)b * NPIX + (size_t)y0 * W;
  int c = x0 + tid;                     // own column, always < 512
  int ch = min(x0 + 64 + tid, W - 1);   // halo column (clamped)
  int ylim = (H - 1) - y0;              // last valid row offset (38 for last band)

  // 2-deep prefetch pipeline: cur = row t, nxt = row t+1
  v2f cur, nxt, curh = {0.f, 0.f}, nxth = {0.f, 0.f};
  cur.x = b1[c];      cur.y = b2[c];
  nxt.x = b1[W + c];  nxt.y = b2[W + c];
  if (halo) {
    curh.x = b1[ch];     curh.y = b2[ch];
    nxth.x = b1[W + ch]; nxth.y = b2[W + ch];
  }

  // vertical ring in registers (compile-time slot after unroll)
  v2f r_ab[13], r_sq[13];
  float r_x[13];
  v2f S_ab = {0.f, 0.f}, S_sq = {0.f, 0.f};
  float S_x = 0.f;
  v2f g_ab = {0.f, 0.f}, g_sq = {0.f, 0.f};
  float g_x = 0.f;
  float acc = 0.f;
  const float inv_n = 1.0f / 169.0f;

  auto step = [&](int t, int slot, bool fill) {
    int buf = t & 1;
    // stage row t (already in registers)
    st[buf][tid] = cur;
    if (halo) st[buf][64 + tid] = curh;

    v2f my = cur;  // own-column value of row t, for global stats

    __syncthreads();  // make staging visible to all lanes (compiler + HW order)

    // rotate pipeline, prefetch row t+2 (clamp binds only on last band tail)
    cur = nxt;
    curh = nxth;
    int yn = (t + 2 > ylim) ? ylim : (t + 2);
    nxt.x = b1[yn * W + c];
    nxt.y = b2[yn * W + c];
    if (halo) {
      nxth.x = b1[yn * W + ch];
      nxth.y = b2[yn * W + ch];
    }

    // global moment accumulation over owned rows
    bool owned = last ? (t >= 13) : (t < BAND_ROWS);
    if (owned) {
      g_ab += my;
      g_sq += my * my;
      g_x = fmaf(my.x, my.y, g_x);
    }

    // horizontal 13-tap sums (packed): 13 pk_add + 13 pk_fma + 13 fma
    v2f h_ab = {0.f, 0.f}, h_sq = {0.f, 0.f};
    float h_x = 0.f;
#pragma unroll
    for (int j = 0; j < P; ++j) {
      v2f v = st[buf][tid + j];
      h_ab += v;
      h_sq += v * v;
      h_x = fmaf(v.x, v.y, h_x);
    }

    // vertical sliding sum via register ring
    if (fill) {
      S_ab += h_ab; S_sq += h_sq; S_x += h_x;
    } else {
      S_ab += h_ab - r_ab[slot];
      S_sq += h_sq - r_sq[slot];
      S_x  += h_x  - r_x[slot];
    }
    r_ab[slot] = h_ab; r_sq[slot] = h_sq; r_x[slot] = h_x;

    // local NCC for output row y0 + t - 12
    // (last band: suppress fill emission — row 473 already owned by band 17;
    //  steady t>=25 emits exactly rows 486..499)
    bool do_out = fill ? (t == 12 && !last) : (!last || t >= 25);
    if (do_out) {
      v2f m = S_ab * inv_n;
      v2f vv = S_sq * inv_n - m * m;
      vv += EPS;
      float cross = fmaf(-S_ab.x * inv_n, S_ab.y, S_x);
      float cc = cross * rsqrtf(vv.x * vv.y);
      acc += valid ? cc : 0.f;
    }
  };

#pragma unroll
  for (int u = 0; u < 13; ++u) step(u, u, true);
#pragma unroll
  for (int s = 0; s < STEADY; ++s) step(13 + s, s % 13, false);

  // wave reductions (single wave per block) + atomics
  float v0 = acc, v1 = g_ab.x, v2 = g_ab.y, v3 = g_sq.x, v4 = g_sq.y, v5 = g_x;
#pragma unroll
  for (int off = 32; off > 0; off >>= 1) {
    v0 += __shfl_down(v0, off, 64);
    v1 += __shfl_down(v1, off, 64);
    v2 += __shfl_down(v2, off, 64);
    v3 += __shfl_down(v3, off, 64);
    v4 += __shfl_down(v4, off, 64);
    v5 += __shfl_down(v5, off, 64);
  }
  if (tid == 0) {
    atomicAdd(&ps[b], v0);
    atomicAdd(&gs[0 * B + b], v1);
    atomicAdd(&gs[1 * B + b], v2);
    atomicAdd(&gs[2 * B + b], v3);
    atomicAdd(&gs[3 * B + b], v4);
    atomicAdd(&gs[4 * B + b], v5);
  }
}

// ---------------------------------------------------------------------------
// Combine: out[b] = 0.5*global_ncc + 0.5*patch_sum/(HP*WP*169)
// ---------------------------------------------------------------------------
__global__ void final_kernel(const float* __restrict__ gs,
                             const float* __restrict__ ps,
                             float* __restrict__ out) {
  int b = threadIdx.x;
  if (b < B) {
    float Nf = (float)NPIX;
    float s1 = gs[0 * B + b];
    float s2 = gs[1 * B + b];
    float s11 = gs[2 * B + b];
    float s22 = gs[3 * B + b];
    float s12 = gs[4 * B + b];
    float m1 = s1 / Nf;
    float m2 = s2 / Nf;
    float v1 = fmaf(-m1, m1, s11 / Nf);
    float v2 = fmaf(-m2, m2, s22 / Nf);
    float cross = fmaf(-Nf * m1, m2, s12);
    float g = cross * rsqrtf((v1 + EPS) * (v2 + EPS)) / Nf;
    float patch = ps[b] / ((float)HP * (float)WP * 169.0f);
    out[b] = 0.5f * g + 0.5f * patch;
  }
}

extern "C" void kernel_launch(void* const* d_in, const int* in_sizes, int n_in,
                              void* d_out, int out_size, void* d_ws, size_t ws_size,
                              hipStream_t stream) {
  const float* x1 = (const float*)d_in[0];
  const float* x2 = (const float*)d_in[1];
  float* out = (float*)d_out;
  float* gs = (float*)d_ws;        // 5*B floats
  float* ps = gs + 5 * B;          // B floats

  hipMemsetAsync(d_ws, 0, 6 * B * sizeof(float), stream);

  ncc_fused_kernel<<<B * TILES_X * BANDS_Y, 64, 0, stream>>>(x1, x2, gs, ps);
  final_kernel<<<1, 64, 0, stream>>>(gs, ps, out);
}